// Round 1
// baseline (470.934 us; speedup 1.0000x reference)
//
#include <hip/hip_runtime.h>
#include <stdint.h>

typedef __attribute__((ext_vector_type(8))) short          s16x8;
typedef __attribute__((ext_vector_type(8))) unsigned short u16x8;
typedef __attribute__((ext_vector_type(4))) unsigned short u16x4;
typedef __attribute__((ext_vector_type(4))) float          f32x4;

#define KPAD  160
#define MROWS 18432
#define NCOLS 4096
#define HWPIX 9216

static __device__ __forceinline__ unsigned short f2bf(float f) {
  unsigned int u = __float_as_uint(f);
  u += 0x7fffu + ((u >> 16) & 1u);
  return (unsigned short)(u >> 16);
}
static __device__ __forceinline__ float bf2f(unsigned short h) {
  return __uint_as_float(((unsigned int)h) << 16);
}

// ---------------------------------------------------------------------------
// prep: bias[n2][p][c] = sum_K9 cols[n2,p,K9]*b2[K9*16+c]
//       A_img[(p*2+n2)][k] = cols (3x3 unfold of x), bf16, k<144 else 0
//       Bt_img[(j*16+c)][k] = w2[j][k*16+c], bf16, k<144 else 0
//       zero d_out (atomics accumulate into it)
// ---------------------------------------------------------------------------
__global__ __launch_bounds__(256)
void ml_prep(const float* __restrict__ x, const float* __restrict__ w2,
             const float* __restrict__ b2,
             unsigned short* __restrict__ Aimg, unsigned short* __restrict__ Btimg,
             float* __restrict__ bias, float* __restrict__ out)
{
  int idx = blockIdx.x * 256 + threadIdx.x;
  if (idx < 18432) {                       // bias
    int n2 = idx / HWPIX, p = idx - n2 * HWPIX;
    int hh = p / 96, ww = p - hh * 96;
    float acc[16];
#pragma unroll
    for (int c = 0; c < 16; c++) acc[c] = 0.f;
    for (int cc = 0; cc < 16; cc++) {
#pragma unroll
      for (int kh = 0; kh < 3; kh++) {
        int ih = hh + kh - 1;
#pragma unroll
        for (int kw = 0; kw < 3; kw++) {
          int iw = ww + kw - 1;
          float xv = 0.f;
          if (ih >= 0 && ih < 96 && iw >= 0 && iw < 96)
            xv = x[((n2 * 16 + cc) * 96 + ih) * 96 + iw];
          const float* b2p = b2 + (cc * 9 + kh * 3 + kw) * 16;
#pragma unroll
          for (int c = 0; c < 16; c++) acc[c] += xv * b2p[c];
        }
      }
    }
    float* bp = bias + idx * 16;
#pragma unroll
    for (int c = 0; c < 16; c++) bp[c] = acc[c];
    return;
  }
  idx -= 18432;
  if (idx < 368640) {                      // A_img: 18432 rows x 20 chunks of 8
    int r = idx / 20, kb = idx - (idx / 20) * 20;
    int p = r >> 1, n2 = r & 1;
    int hh = p / 96, ww = p - hh * 96;
    u16x8 v;
#pragma unroll
    for (int t = 0; t < 8; t++) {
      int k = kb * 8 + t;
      float xv = 0.f;
      if (k < 144) {
        int cc = k / 9, kidx = k - cc * 9;
        int ih = hh + kidx / 3 - 1, iw = ww + (kidx % 3) - 1;
        if (ih >= 0 && ih < 96 && iw >= 0 && iw < 96)
          xv = x[((n2 * 16 + cc) * 96 + ih) * 96 + iw];
      }
      v[t] = f2bf(xv);
    }
    *(u16x8*)(Aimg + r * KPAD + kb * 8) = v;
    return;
  }
  idx -= 368640;
  if (idx < 81920) {                       // Bt_img: 4096 rows x 20 chunks
    int n = idx / 20, kb = idx - (idx / 20) * 20;
    int j = n >> 4, c = n & 15;
    u16x8 v;
#pragma unroll
    for (int t = 0; t < 8; t++) {
      int k = kb * 8 + t;
      v[t] = (k < 144) ? f2bf(w2[j * 2304 + k * 16 + c]) : (unsigned short)0;
    }
    *(u16x8*)(Btimg + n * KPAD + kb * 8) = v;
    return;
  }
  idx -= 81920;
  if (idx < 294912) {                      // zero d_out (1179648 f32)
    f32x4 z = {0.f, 0.f, 0.f, 0.f};
    ((f32x4*)out)[idx] = z;
  }
}

// ---------------------------------------------------------------------------
// main fused GEMM + h-fold kernel
// grid (144, 16): bx = m-strip (128 rows = 64 p x 2 n), by = col block (256 = 16 j x 16 c)
// ---------------------------------------------------------------------------
struct SmemT {
  union {
    struct {
      unsigned short A[2][128 * 32];   // 16 KB
      unsigned short B[2][256 * 32];   // 32 KB
    } m;
    float ob[64 * 129];                // 33 KB (padded stride 129)
  } u;
  unsigned short hbuf[64 * 16 * 4];    // 8 KB: [p_l][jl][q] bf16
};

struct StageRegs { u16x8 a[2]; u16x8 b[4]; };

static __device__ __forceinline__ void stage_load(StageRegs& r,
    const unsigned short* __restrict__ Aimg, const unsigned short* __restrict__ Btimg,
    int m0, int n0, int ks, int tid)
{
#pragma unroll
  for (int ci = 0; ci < 2; ci++) {
    int flat = ci * 256 + tid;
    int row = flat >> 2, kq = flat & 3;
    r.a[ci] = *(const u16x8*)(Aimg + (m0 + row) * KPAD + ks * 32 + kq * 8);
  }
#pragma unroll
  for (int ci = 0; ci < 4; ci++) {
    int flat = ci * 256 + tid;
    int col = flat >> 2, kq = flat & 3;
    r.b[ci] = *(const u16x8*)(Btimg + (n0 + col) * KPAD + ks * 32 + kq * 8);
  }
}

static __device__ __forceinline__ void stage_write(const StageRegs& r,
    unsigned short* As, unsigned short* Bs, int tid)
{
#pragma unroll
  for (int ci = 0; ci < 2; ci++) {
    int flat = ci * 256 + tid;
    int row = flat >> 2, kq = flat & 3;
    *(u16x8*)(As + row * 32 + ((kq ^ ((row >> 1) & 3)) << 3)) = r.a[ci];
  }
#pragma unroll
  for (int ci = 0; ci < 4; ci++) {
    int flat = ci * 256 + tid;
    int col = flat >> 2, kq = flat & 3;
    *(u16x8*)(Bs + col * 32 + ((kq ^ ((col >> 1) & 3)) << 3)) = r.b[ci];
  }
}

static __device__ __forceinline__ void compute_step(f32x4 (&acc)[8][4],
    const unsigned short* As, const unsigned short* Bs, int lane, int wid)
{
  s16x8 af[8]; s16x8 bfr[4];
  int kq = lane >> 4;
#pragma unroll
  for (int mi = 0; mi < 8; mi++) {
    int row = mi * 16 + (lane & 15);
    af[mi] = *(const s16x8*)(As + row * 32 + ((kq ^ ((row >> 1) & 3)) << 3));
  }
#pragma unroll
  for (int ni = 0; ni < 4; ni++) {
    int col = wid * 64 + ni * 16 + (lane & 15);
    bfr[ni] = *(const s16x8*)(Bs + col * 32 + ((kq ^ ((col >> 1) & 3)) << 3));
  }
#pragma unroll
  for (int mi = 0; mi < 8; mi++)
#pragma unroll
    for (int ni = 0; ni < 4; ni++)
      acc[mi][ni] = __builtin_amdgcn_mfma_f32_16x16x32_bf16(af[mi], bfr[ni], acc[mi][ni], 0, 0, 0);
}

__global__ __launch_bounds__(256, 2)
void ml_main(const unsigned short* __restrict__ Aimg,
             const unsigned short* __restrict__ Btimg,
             const float* __restrict__ bias,
             const float* __restrict__ pos, const float* __restrict__ w1,
             const float* __restrict__ b1,
             float* __restrict__ out)
{
  __shared__ SmemT sm;
  const int tid  = threadIdx.x;
  const int lane = tid & 63;
  const int wid  = tid >> 6;
  const int bx = blockIdx.x;           // 0..143
  const int by = blockIdx.y;           // 0..15
  const int p0 = bx * 64;
  const int m0 = bx * 128;
  const int n0 = by * 256;
  const int j0 = by * 16;

  // ---- stage h weights on the fly: hbuf[p_l][jl][q] ----
  {
    int p_l = tid >> 2, q = tid & 3;
    int p = p0 + p_l;
    int hh = p / 96, ww = p - hh * 96;
    int si = q >> 1, sj = q & 1;
    int m = hh * 384 + si * 192 + ww * 2 + sj;
    float pv0 = pos[m * 3 + 0], pv1 = pos[m * 3 + 1], pv2 = pos[m * 3 + 2];
#pragma unroll
    for (int jl = 0; jl < 16; jl++) {
      int j = j0 + jl;
      float hv = pv0 * w1[j] + pv1 * w1[256 + j] + pv2 * w1[512 + j] + b1[j];
      hv = (hv >= 0.f) ? hv : 0.2f * hv;
      sm.hbuf[(p_l * 16 + jl) * 4 + q] = f2bf(hv);
    }
  }

  f32x4 acc[8][4];
#pragma unroll
  for (int mi = 0; mi < 8; mi++)
#pragma unroll
    for (int ni = 0; ni < 4; ni++) {
      f32x4 z = {0.f, 0.f, 0.f, 0.f};
      acc[mi][ni] = z;
    }

  // ---- K loop: 5 steps of BK=32, double buffered, loads issued before compute ----
  StageRegs sr;
  stage_load(sr, Aimg, Btimg, m0, n0, 0, tid);
  stage_write(sr, sm.u.m.A[0], sm.u.m.B[0], tid);
  __syncthreads();
#pragma unroll 1
  for (int ks = 0; ks < 5; ks++) {
    int b = ks & 1;
    if (ks < 4) stage_load(sr, Aimg, Btimg, m0, n0, ks + 1, tid);
    compute_step(acc, sm.u.m.A[b], sm.u.m.B[b], lane, wid);
    if (ks < 4) stage_write(sr, sm.u.m.A[b ^ 1], sm.u.m.B[b ^ 1], tid);
    __syncthreads();
  }

  // ---- init out tile (bias only from by==0, else zero) ----
  for (int i = tid; i < 64 * 129; i += 256) {
    int p_l = i / 129, off = i - p_l * 129;
    float v = 0.f;
    if (by == 0 && off < 128) {
      int n2 = (off >> 4) & 1, c = off & 15;
      v = bias[((n2 * HWPIX) + p0 + p_l) * 16 + c];   // same bias for all 4 q slots
    }
    sm.u.ob[i] = v;
  }
  __syncthreads();

  // ---- epilogue: fold j with h weights, ds_add into padded LDS tile ----
  {
    const int c_lane = lane & 15;
    const int rowb = (lane >> 4) * 4;
#pragma unroll
    for (int mi = 0; mi < 8; mi++) {
      int r0 = mi * 16 + rowb;       // even
      int pl0 = r0 >> 1, pl1 = pl0 + 1;
      float tmp[4][4];
#pragma unroll
      for (int i2 = 0; i2 < 4; i2++)
#pragma unroll
        for (int q = 0; q < 4; q++) tmp[i2][q] = 0.f;
#pragma unroll
      for (int ni = 0; ni < 4; ni++) {
        int jl = wid * 4 + ni;
        u16x4 h0 = *(const u16x4*)(&sm.hbuf[(pl0 * 16 + jl) * 4]);
        u16x4 h1 = *(const u16x4*)(&sm.hbuf[(pl1 * 16 + jl) * 4]);
        f32x4 v = acc[mi][ni];
#pragma unroll
        for (int q = 0; q < 4; q++) {
          float h0f = bf2f((unsigned short)h0[q]);
          float h1f = bf2f((unsigned short)h1[q]);
          tmp[0][q] += h0f * v[0];
          tmp[1][q] += h0f * v[1];
          tmp[2][q] += h1f * v[2];
          tmp[3][q] += h1f * v[3];
        }
      }
#pragma unroll
      for (int i2 = 0; i2 < 4; i2++) {
        int pl = (i2 < 2) ? pl0 : pl1;
        int n2 = i2 & 1;
#pragma unroll
        for (int q = 0; q < 4; q++)
          atomicAdd(&sm.u.ob[pl * 129 + (q * 2 + n2) * 16 + c_lane], tmp[i2][q]);
      }
    }
  }
  __syncthreads();

  // ---- coalesced atomic writeout: flat = n2(1) c(4) si(1) p_l(6) sj(1) ----
#pragma unroll 1
  for (int it = 0; it < 32; it++) {
    int flat = it * 256 + tid;
    int sj  = flat & 1;
    int p_l = (flat >> 1) & 63;
    int si  = (flat >> 7) & 1;
    int c   = (flat >> 8) & 15;
    int n2  = flat >> 12;
    int q = si * 2 + sj;
    float v = sm.u.ob[p_l * 129 + (q * 2 + n2) * 16 + c];
    int p = p0 + p_l;
    int y = (p / 96) * 2 + si;
    int xx = (p - (p / 96) * 96) * 2 + sj;
    atomicAdd(&out[((n2 * 16 + c) * 192 + y) * 192 + xx], v);
  }
}

// ---------------------------------------------------------------------------
extern "C" void kernel_launch(void* const* d_in, const int* in_sizes, int n_in,
                              void* d_out, int out_size, void* d_ws, size_t ws_size,
                              hipStream_t stream) {
  const float* x   = (const float*)d_in[0];
  const float* pos = (const float*)d_in[1];
  // d_in[2] = mask (all true) -- unused
  const float* w1  = (const float*)d_in[3];
  const float* b1  = (const float*)d_in[4];
  const float* w2  = (const float*)d_in[5];
  const float* b2  = (const float*)d_in[6];
  float* out = (float*)d_out;

  unsigned short* Aimg  = (unsigned short*)d_ws;            // 18432*160*2 B
  unsigned short* Btimg = Aimg + MROWS * KPAD;              // 4096*160*2 B
  float* bias = (float*)(Btimg + NCOLS * KPAD);             // 2*9216*16*4 B

  // prep: 18432 + 368640 + 81920 + 294912 = 763904 items = 2984 * 256
  ml_prep<<<2984, 256, 0, stream>>>(x, w2, b2, Aimg, Btimg, bias, out);
  ml_main<<<dim3(144, 16), 256, 0, stream>>>(Aimg, Btimg, bias, pos, w1, b1, out);
}

// Round 2
// 121.382 us; speedup vs baseline: 3.8798x; 3.8798x over previous
//
#include <hip/hip_runtime.h>
#include <stdint.h>

typedef __attribute__((ext_vector_type(8))) short          s16x8;
typedef __attribute__((ext_vector_type(8))) unsigned short u16x8;
typedef __attribute__((ext_vector_type(4))) unsigned short u16x4;
typedef __attribute__((ext_vector_type(4))) float          f32x4;

#define KPAD  160
#define MROWS 18432
#define HWPIX 9216
#define OUTSZ 1179648
#define GSTR  264      // u16 per G-LDS row (32 rows); 264*2=528B, 16B aligned, banks vary with row

static __device__ __forceinline__ unsigned short f2bf(float f) {
  unsigned int u = __float_as_uint(f);
  u += 0x7fffu + ((u >> 16) & 1u);
  return (unsigned short)(u >> 16);
}
static __device__ __forceinline__ float bf2f(unsigned short h) {
  return __uint_as_float(((unsigned int)h) << 16);
}

// ---------------------------------------------------------------------------
// prep: bias[n2][p][c] = sum_K9 cols[n2,p,K9]*b2[K9*16+c]
//       A_img[(p*2+n2)][k] = 3x3 unfold of x, bf16, k<144 else 0
//       Bt_img[(j*16+c)][k] = w2[j][k*16+c], bf16
// ---------------------------------------------------------------------------
__global__ __launch_bounds__(256)
void ml_prep(const float* __restrict__ x, const float* __restrict__ w2,
             const float* __restrict__ b2,
             unsigned short* __restrict__ Aimg, unsigned short* __restrict__ Btimg,
             float* __restrict__ bias)
{
  int idx = blockIdx.x * 256 + threadIdx.x;
  if (idx < 18432) {                       // bias
    int n2 = idx / HWPIX, p = idx - n2 * HWPIX;
    int hh = p / 96, ww = p - hh * 96;
    float acc[16];
#pragma unroll
    for (int c = 0; c < 16; c++) acc[c] = 0.f;
    for (int cc = 0; cc < 16; cc++) {
#pragma unroll
      for (int kh = 0; kh < 3; kh++) {
        int ih = hh + kh - 1;
#pragma unroll
        for (int kw = 0; kw < 3; kw++) {
          int iw = ww + kw - 1;
          float xv = 0.f;
          if (ih >= 0 && ih < 96 && iw >= 0 && iw < 96)
            xv = x[((n2 * 16 + cc) * 96 + ih) * 96 + iw];
          const float* b2p = b2 + (cc * 9 + kh * 3 + kw) * 16;
#pragma unroll
          for (int c = 0; c < 16; c++) acc[c] += xv * b2p[c];
        }
      }
    }
    float* bp = bias + idx * 16;
#pragma unroll
    for (int c = 0; c < 16; c++) bp[c] = acc[c];
    return;
  }
  idx -= 18432;
  if (idx < 368640) {                      // A_img
    int r = idx / 20, kb = idx - (idx / 20) * 20;
    int p = r >> 1, n2 = r & 1;
    int hh = p / 96, ww = p - hh * 96;
    u16x8 v;
#pragma unroll
    for (int t = 0; t < 8; t++) {
      int k = kb * 8 + t;
      float xv = 0.f;
      if (k < 144) {
        int cc = k / 9, kidx = k - cc * 9;
        int ih = hh + kidx / 3 - 1, iw = ww + (kidx % 3) - 1;
        if (ih >= 0 && ih < 96 && iw >= 0 && iw < 96)
          xv = x[((n2 * 16 + cc) * 96 + ih) * 96 + iw];
      }
      v[t] = f2bf(xv);
    }
    *(u16x8*)(Aimg + r * KPAD + kb * 8) = v;
    return;
  }
  idx -= 368640;
  if (idx < 81920) {                       // Bt_img
    int n = idx / 20, kb = idx - (idx / 20) * 20;
    int j = n >> 4, c = n & 15;
    u16x8 v;
#pragma unroll
    for (int t = 0; t < 8; t++) {
      int k = kb * 8 + t;
      v[t] = (k < 144) ? f2bf(w2[j * 2304 + k * 16 + c]) : (unsigned short)0;
    }
    *(u16x8*)(Btimg + n * KPAD + kb * 8) = v;
  }
}

// ---------------------------------------------------------------------------
// main: grid (144, 4). Block = 128 M-rows x 64 j's (4 j-blocks of 16).
// Per j-block: GEMM 128x256 (K=160), dump G to LDS bf16, fold j with h into
// per-thread register accumulators. Store folded partial to ws (no atomics).
// ---------------------------------------------------------------------------
struct SmemT {
  union {
    struct {
      unsigned short A[2][128 * 32];   // 16 KB
      unsigned short B[2][256 * 32];   // 32 KB
    } m;
    unsigned short G[32 * GSTR];       // 16.5 KB (union: used after K-loop)
  } u;
  unsigned short hbuf[4 * 64 * 24];    // 12 KB: [q][p_l][jl(pad 24)]
};

struct StageRegs { u16x8 a[2]; u16x8 b[4]; };

static __device__ __forceinline__ void stage_load(StageRegs& r,
    const unsigned short* __restrict__ Aimg, const unsigned short* __restrict__ Btimg,
    int m0, int n0, int ks, int tid)
{
#pragma unroll
  for (int ci = 0; ci < 2; ci++) {
    int flat = ci * 256 + tid;
    int row = flat >> 2, kq = flat & 3;
    r.a[ci] = *(const u16x8*)(Aimg + (m0 + row) * KPAD + ks * 32 + kq * 8);
  }
#pragma unroll
  for (int ci = 0; ci < 4; ci++) {
    int flat = ci * 256 + tid;
    int col = flat >> 2, kq = flat & 3;
    r.b[ci] = *(const u16x8*)(Btimg + (n0 + col) * KPAD + ks * 32 + kq * 8);
  }
}

static __device__ __forceinline__ void stage_write(const StageRegs& r,
    unsigned short* As, unsigned short* Bs, int tid)
{
#pragma unroll
  for (int ci = 0; ci < 2; ci++) {
    int flat = ci * 256 + tid;
    int row = flat >> 2, kq = flat & 3;
    *(u16x8*)(As + row * 32 + ((kq ^ ((row >> 1) & 3)) << 3)) = r.a[ci];
  }
#pragma unroll
  for (int ci = 0; ci < 4; ci++) {
    int flat = ci * 256 + tid;
    int col = flat >> 2, kq = flat & 3;
    *(u16x8*)(Bs + col * 32 + ((kq ^ ((col >> 1) & 3)) << 3)) = r.b[ci];
  }
}

static __device__ __forceinline__ void compute_step(f32x4 (&acc)[8][4],
    const unsigned short* As, const unsigned short* Bs, int lane, int wid)
{
  s16x8 af[8]; s16x8 bfr[4];
  int kq = lane >> 4;
#pragma unroll
  for (int mi = 0; mi < 8; mi++) {
    int row = mi * 16 + (lane & 15);
    af[mi] = *(const s16x8*)(As + row * 32 + ((kq ^ ((row >> 1) & 3)) << 3));
  }
#pragma unroll
  for (int ni = 0; ni < 4; ni++) {
    int col = wid * 64 + ni * 16 + (lane & 15);
    bfr[ni] = *(const s16x8*)(Bs + col * 32 + ((kq ^ ((col >> 1) & 3)) << 3));
  }
#pragma unroll
  for (int mi = 0; mi < 8; mi++)
#pragma unroll
    for (int ni = 0; ni < 4; ni++)
      acc[mi][ni] = __builtin_amdgcn_mfma_f32_16x16x32_bf16(af[mi], bfr[ni], acc[mi][ni], 0, 0, 0);
}

__global__ __launch_bounds__(256, 2)
void ml_main(const unsigned short* __restrict__ Aimg,
             const unsigned short* __restrict__ Btimg,
             const float* __restrict__ pos, const float* __restrict__ w1,
             const float* __restrict__ b1,
             float* __restrict__ part)
{
  __shared__ SmemT sm;
  const int tid  = threadIdx.x;
  const int lane = tid & 63;
  const int wid  = tid >> 6;
  const int bx = blockIdx.x;           // 0..143  (M strip: 128 rows = 64 p x 2 n)
  const int by = blockIdx.y;           // 0..3    (j group: 64 j's)
  const int p0 = bx * 64;
  const int m0 = bx * 128;

  // thread's fold identity (fixed): output (sj, pl, si, c-low2=wid)
  const int f_sj = tid & 1;
  const int f_pl = (tid >> 1) & 15;
  const int f_si = (tid >> 5) & 1;
  const int f_q  = f_si * 2 + f_sj;
  const int f_cl = wid;                // c low 2 bits

  // pos for hbuf compute (thread -> (p_l = tid>>2, q = tid&3)), loaded once
  const int h_pl = tid >> 2, h_q = tid & 3;
  float pv0, pv1, pv2;
  {
    int p = p0 + h_pl;
    int hh = p / 96, ww = p - hh * 96;
    int si = h_q >> 1, sj = h_q & 1;
    int m = hh * 384 + si * 192 + ww * 2 + sj;
    pv0 = pos[m * 3 + 0]; pv1 = pos[m * 3 + 1]; pv2 = pos[m * 3 + 2];
  }

  float out_acc[4][8];
#pragma unroll
  for (int ch = 0; ch < 4; ch++)
#pragma unroll
    for (int it = 0; it < 8; it++) out_acc[ch][it] = 0.f;

#pragma unroll 1
  for (int jbl = 0; jbl < 4; jbl++) {
    const int j0 = (by * 4 + jbl) * 16;
    const int n0 = j0 * 16;

    __syncthreads();   // protect hbuf + staging (G union) from previous fold readers

    // ---- hbuf[q][p_l][jl] for this j-block ----
#pragma unroll 1
    for (int jl = 0; jl < 16; jl++) {
      int j = j0 + jl;
      float hv = pv0 * w1[j] + pv1 * w1[256 + j] + pv2 * w1[512 + j] + b1[j];
      hv = (hv >= 0.f) ? hv : 0.2f * hv;
      sm.hbuf[(h_q * 64 + h_pl) * 24 + jl] = f2bf(hv);
    }

    // ---- GEMM: K loop, 5 steps of BK=32, double buffered ----
    f32x4 acc[8][4];
#pragma unroll
    for (int mi = 0; mi < 8; mi++)
#pragma unroll
      for (int ni = 0; ni < 4; ni++) {
        f32x4 z = {0.f, 0.f, 0.f, 0.f};
        acc[mi][ni] = z;
      }

    StageRegs sr;
    stage_load(sr, Aimg, Btimg, m0, n0, 0, tid);
    stage_write(sr, sm.u.m.A[0], sm.u.m.B[0], tid);
    __syncthreads();
#pragma unroll 1
    for (int ks = 0; ks < 5; ks++) {
      int b = ks & 1;
      if (ks < 4) stage_load(sr, Aimg, Btimg, m0, n0, ks + 1, tid);
      compute_step(acc, sm.u.m.A[b], sm.u.m.B[b], lane, wid);
      if (ks < 4) stage_write(sr, sm.u.m.A[b ^ 1], sm.u.m.B[b ^ 1], tid);
      __syncthreads();
    }

    // ---- per-chunk: dump 32 G-rows to LDS (bf16), fold with h ----
#pragma unroll
    for (int ch = 0; ch < 4; ch++) {
      // dump: frag (mi = ch*2+mm, ni), rows (lane>>4)*4+reg, col c=lane&15, jl=wid*4+ni
#pragma unroll
      for (int mm = 0; mm < 2; mm++) {
#pragma unroll
        for (int reg = 0; reg < 4; reg++) {
          int row = mm * 16 + (lane >> 4) * 4 + reg;
          u16x4 v4;
          v4[0] = f2bf(acc[ch * 2 + mm][0][reg]);
          v4[1] = f2bf(acc[ch * 2 + mm][1][reg]);
          v4[2] = f2bf(acc[ch * 2 + mm][2][reg]);
          v4[3] = f2bf(acc[ch * 2 + mm][3][reg]);
          *(u16x4*)(&sm.u.G[row * GSTR + (lane & 15) * 16 + wid * 4]) = v4;
        }
      }
      __syncthreads();

      // fold: thread owns outputs (p = p0+ch*16+f_pl, q=f_q, n2/c-high from it)
      float hv[16];
      {
        const unsigned short* hb = &sm.hbuf[(f_q * 64 + ch * 16 + f_pl) * 24];
        u16x8 h0 = *(const u16x8*)hb;
        u16x8 h1 = *(const u16x8*)(hb + 8);
#pragma unroll
        for (int t = 0; t < 8; t++) { hv[t] = bf2f((unsigned short)h0[t]); hv[8 + t] = bf2f((unsigned short)h1[t]); }
      }
#pragma unroll
      for (int it = 0; it < 8; it++) {
        int c  = f_cl | ((it & 3) << 2);
        int n2 = it >> 2;
        int row = f_pl * 2 + n2;
        const unsigned short* gp = &sm.u.G[row * GSTR + c * 16];
        u16x8 g0 = *(const u16x8*)gp;
        u16x8 g1 = *(const u16x8*)(gp + 8);
        float s = 0.f;
#pragma unroll
        for (int t = 0; t < 8; t++) s += hv[t] * bf2f((unsigned short)g0[t]);
#pragma unroll
        for (int t = 0; t < 8; t++) s += hv[8 + t] * bf2f((unsigned short)g1[t]);
        out_acc[ch][it] += s;
      }
      __syncthreads();   // fold done before next dump / next j-block staging
    }
  }

  // ---- store folded partial: part[by][((n2*16+c)*192+y)*192+x], plain stores ----
#pragma unroll
  for (int ch = 0; ch < 4; ch++) {
#pragma unroll
    for (int it = 0; it < 8; it++) {
      int c  = f_cl | ((it & 3) << 2);
      int n2 = it >> 2;
      int p  = p0 + ch * 16 + f_pl;
      int hh = p / 96, ww = p - hh * 96;
      int y = hh * 2 + f_si, xx = ww * 2 + f_sj;
      part[by * OUTSZ + ((n2 * 16 + c) * 192 + y) * 192 + xx] = out_acc[ch][it];
    }
  }
}

// ---------------------------------------------------------------------------
// reduce: out = bias + sum of 4 partials. Coalesced f32x4.
// ---------------------------------------------------------------------------
__global__ __launch_bounds__(256)
void ml_reduce(const float* __restrict__ part, const float* __restrict__ bias,
               float* __restrict__ out)
{
  int i = blockIdx.x * 256 + threadIdx.x;      // 0..294911
  int e = i * 4;
  f32x4 s = *(const f32x4*)(part + e);
  s += *(const f32x4*)(part + OUTSZ + e);
  s += *(const f32x4*)(part + 2 * OUTSZ + e);
  s += *(const f32x4*)(part + 3 * OUTSZ + e);
  int x0 = e % 192;
  int yy = (e / 192) % 192;
  int cc = (e / 36864) & 15;
  int n2 = e / 589824;
  int prow = (yy >> 1) * 96;
  f32x4 r;
#pragma unroll
  for (int t = 0; t < 4; t++) {
    int p = prow + ((x0 + t) >> 1);
    r[t] = s[t] + bias[(n2 * HWPIX + p) * 16 + cc];
  }
  *(f32x4*)(out + e) = r;
}

// ---------------------------------------------------------------------------
extern "C" void kernel_launch(void* const* d_in, const int* in_sizes, int n_in,
                              void* d_out, int out_size, void* d_ws, size_t ws_size,
                              hipStream_t stream) {
  const float* x   = (const float*)d_in[0];
  const float* pos = (const float*)d_in[1];
  // d_in[2] = mask (all true) -- unused
  const float* w1  = (const float*)d_in[3];
  const float* b1  = (const float*)d_in[4];
  const float* w2  = (const float*)d_in[5];
  const float* b2  = (const float*)d_in[6];
  float* out = (float*)d_out;

  unsigned short* Aimg  = (unsigned short*)d_ws;            // 5,898,240 B
  unsigned short* Btimg = Aimg + MROWS * KPAD;              // 1,310,720 B
  float* bias = (float*)(Btimg + 4096 * KPAD);              // 1,179,648 B
  float* part = bias + MROWS * 16;                          // 4*OUTSZ*4 = 18,874,368 B

  // prep: 18432 + 368640 + 81920 = 468992 = 1832 * 256
  ml_prep<<<1832, 256, 0, stream>>>(x, w2, b2, Aimg, Btimg, bias);
  ml_main<<<dim3(144, 4), 256, 0, stream>>>(Aimg, Btimg, pos, w1, b1, part);
  ml_reduce<<<1152, 256, 0, stream>>>(part, bias, out);
}

// Round 4
// 80.863 us; speedup vs baseline: 5.8238x; 1.5011x over previous
//
#include <hip/hip_runtime.h>
#include <stdint.h>

typedef __attribute__((ext_vector_type(8))) short          s16x8;
typedef __attribute__((ext_vector_type(8))) unsigned short u16x8;
typedef __attribute__((ext_vector_type(4))) float          f32x4;

#define KPAD  160
#define MROWS 18432
#define HWPIX 9216
#define ASTR  168           // padded LDS A row stride (u16): conflict-free frag reads
#define OSTR  68            // padded outr row stride (f32)

static __device__ __forceinline__ unsigned short f2bf(float f) {
  unsigned int u = __float_as_uint(f);
  u += 0x7fffu + ((u >> 16) & 1u);
  return (unsigned short)(u >> 16);
}

// ---------------------------------------------------------------------------
// prep: A_img[(p*2+n2)][k] = 3x3 unfold of x (bf16, k<144 else 0)
//       Bt_img[n][k]: n<4096 -> w2[j][k*16+c] (n=j*16+c); n>=4096 -> bias
//       block: col 4096+c = b2[k*16+c] (jl==0), cols for jl 1..15 = 0.
// ---------------------------------------------------------------------------
__global__ __launch_bounds__(256)
void ml_prep(const float* __restrict__ x, const float* __restrict__ w2,
             const float* __restrict__ b2,
             unsigned short* __restrict__ Aimg, unsigned short* __restrict__ Btimg)
{
  int idx = blockIdx.x * 256 + threadIdx.x;
  if (idx < 368640) {                      // A_img: 18432 rows x 20 chunks of 8
    int r = idx / 20, kb = idx - (idx / 20) * 20;
    int p = r >> 1, n2 = r & 1;
    int hh = p / 96, ww = p - hh * 96;
    u16x8 v;
#pragma unroll
    for (int t = 0; t < 8; t++) {
      int k = kb * 8 + t;
      float xv = 0.f;
      if (k < 144) {
        int cc = k / 9, kidx = k - cc * 9;
        int ih = hh + kidx / 3 - 1, iw = ww + (kidx % 3) - 1;
        if (ih >= 0 && ih < 96 && iw >= 0 && iw < 96)
          xv = x[((n2 * 16 + cc) * 96 + ih) * 96 + iw];
      }
      v[t] = f2bf(xv);
    }
    *(u16x8*)(Aimg + r * KPAD + kb * 8) = v;
    return;
  }
  idx -= 368640;
  if (idx < 87040) {                       // Bt_img: 4352 rows x 20 chunks
    int n = idx / 20, kb = idx - (idx / 20) * 20;
    u16x8 v;
    if (n < 4096) {
      int j = n >> 4, c = n & 15;
#pragma unroll
      for (int t = 0; t < 8; t++) {
        int k = kb * 8 + t;
        v[t] = (k < 144) ? f2bf(w2[j * 2304 + k * 16 + c]) : (unsigned short)0;
      }
    } else {
      int m = n - 4096;
      int jl = m >> 4, c = m & 15;
#pragma unroll
      for (int t = 0; t < 8; t++) {
        int k = kb * 8 + t;
        v[t] = (jl == 0 && k < 144) ? f2bf(b2[k * 16 + c]) : (unsigned short)0;
      }
    }
    *(u16x8*)(Btimg + n * KPAD + kb * 8) = v;
  }
}

// ---------------------------------------------------------------------------
// main: grid(288). Block = 64 M-rows (32 p x 2 n2) x ALL 4352 N-cols.
// Per j-block (17): GEMM 64x256 (K=160, BK=32, B direct-from-global with
// depth-1 register prefetch, A in padded LDS), then register fold over jl
// with f32 h from LDS. B prefetch buffers are passed in parity-swapped
// order per j-block (5 K-steps flip parity) so all indices stay
// compile-time. Cross-wave reduce in LDS, single coalesced writeout.
// ---------------------------------------------------------------------------
struct SmemT {
  unsigned short A[64 * ASTR];   // 21504 B (aliased by outr after compute)
  float hbuf[2][32 * OSTR];      // 2 x 8704 B : [p_l][jl*4+q], row stride 68
};

static __device__ __forceinline__ void load_bfrag(s16x8* br,
    const unsigned short* __restrict__ Bt, int n0, int ks, int lane, int wid)
{
#pragma unroll
  for (int ni = 0; ni < 4; ni++) {
    int col = wid * 64 + ni * 16 + (lane & 15);
    br[ni] = *(const s16x8*)(Bt + (n0 + col) * KPAD + ks * 32 + (lane >> 4) * 8);
  }
}

__global__ __launch_bounds__(256, 2)
void ml_main(const unsigned short* __restrict__ Aimg,
             const unsigned short* __restrict__ Btimg,
             const float* __restrict__ pos, const float* __restrict__ w1,
             const float* __restrict__ b1,
             float* __restrict__ out)
{
  __shared__ SmemT sm;
  const int tid  = threadIdx.x;
  const int lane = tid & 63;
  const int wid  = tid >> 6;
  const int bx   = blockIdx.x;       // 0..287
  const int m0   = bx * 64;
  const int p0   = bx * 32;

  // ---- stage A (64 rows x 160 k) into padded LDS; 5 chunks/thread ----
  u16x8 av[5];
  int arow[5], akb[5];
#pragma unroll
  for (int i = 0; i < 5; i++) {
    int id = i * 256 + tid;          // 0..1279
    arow[i] = id / 20; akb[i] = id - (id / 20) * 20;
    av[i] = *(const u16x8*)(Aimg + (m0 + arow[i]) * KPAD + akb[i] * 8);
  }

  // ---- per-thread pos values: p = p0 + (tid>>3), all 4 q ----
  float pv[4][3];
  {
    int p = p0 + (tid >> 3);
    int hh = p / 96, ww = p - hh * 96;
#pragma unroll
    for (int q = 0; q < 4; q++) {
      int m = hh * 384 + (q >> 1) * 192 + ww * 2 + (q & 1);
      pv[q][0] = pos[m * 3 + 0];
      pv[q][1] = pos[m * 3 + 1];
      pv[q][2] = pos[m * 3 + 2];
    }
  }

#pragma unroll
  for (int i = 0; i < 5; i++)
    *(u16x8*)(sm.A + arow[i] * ASTR + akb[i] * 8) = av[i];

  // ---- B prefetch buffers (named; parity handled at call sites) ----
  s16x8 br0[4], br1[4];
  load_bfrag(br0, Btimg, 0, 0, lane, wid);

  f32x4 oa[4][4];                    // [mi][reg] over q
#pragma unroll
  for (int mi = 0; mi < 4; mi++)
#pragma unroll
    for (int reg = 0; reg < 4; reg++) {
      f32x4 z = {0.f, 0.f, 0.f, 0.f};
      oa[mi][reg] = z;
    }

  __syncthreads();                   // A staged

  // jblock: bx0 = buffer holding (jb, ks=0); even ks compute bx0, odd bx1;
  // final prefetch of (jb+1, 0) lands in bx1 -> caller swaps for next jb.
  auto jblock = [&](int jb, s16x8 (&bx0)[4], s16x8 (&bx1)[4]) {
    // ---- hbuf[jb&1]: h[p][jl][q] f32 (bias block: jl==0 -> 1 else 0) ----
    {
      float* hb = sm.hbuf[jb & 1];
      int p_h = tid >> 3, sub = tid & 7;
#pragma unroll
      for (int t = 0; t < 2; t++) {
        int jl = sub + t * 8;
        f32x4 hv;
        if (jb < 16) {
          int j = jb * 16 + jl;
          float wa = w1[j], wb = w1[256 + j], wc = w1[512 + j], bb = b1[j];
#pragma unroll
          for (int q = 0; q < 4; q++) {
            float h = pv[q][0] * wa + pv[q][1] * wb + pv[q][2] * wc + bb;
            hv[q] = (h >= 0.f) ? h : 0.2f * h;
          }
        } else {
          float v = (jl == 0) ? 1.f : 0.f;
          hv[0] = v; hv[1] = v; hv[2] = v; hv[3] = v;
        }
        *(f32x4*)&hb[p_h * OSTR + jl * 4] = hv;
      }
    }
    __syncthreads();                 // hbuf visible (dbuf protects prev readers)

    // ---- GEMM 64 x 256, K=160 (5 steps), B global-direct prefetched ----
    f32x4 acc[4][4];
#pragma unroll
    for (int mi = 0; mi < 4; mi++)
#pragma unroll
      for (int ni = 0; ni < 4; ni++) {
        f32x4 z = {0.f, 0.f, 0.f, 0.f};
        acc[mi][ni] = z;
      }

#pragma unroll
    for (int ks = 0; ks < 5; ks++) {
      s16x8 (&bcur)[4]  = (ks & 1) ? bx1 : bx0;   // compile-time under unroll
      s16x8 (&bnext)[4] = (ks & 1) ? bx0 : bx1;
      if (!(jb == 16 && ks == 4)) {
        int njb = (ks < 4) ? jb : jb + 1;
        int nks = (ks < 4) ? ks + 1 : 0;
        load_bfrag(bnext, Btimg, njb * 256, nks, lane, wid);
      }
      s16x8 af[4];
#pragma unroll
      for (int mi = 0; mi < 4; mi++) {
        int row = mi * 16 + (lane & 15);
        af[mi] = *(const s16x8*)(sm.A + row * ASTR + ks * 32 + (lane >> 4) * 8);
      }
#pragma unroll
      for (int mi = 0; mi < 4; mi++)
#pragma unroll
        for (int ni = 0; ni < 4; ni++)
          acc[mi][ni] = __builtin_amdgcn_mfma_f32_16x16x32_bf16(af[mi], bcur[ni], acc[mi][ni], 0, 0, 0);
    }

    // ---- register fold over this j-block's 16 jl (wave owns jl = wid*4+ni) ----
    {
      const float* hb = sm.hbuf[jb & 1];
#pragma unroll
      for (int mi = 0; mi < 4; mi++) {
        int pb = mi * 8 + (lane >> 4) * 2;
#pragma unroll
        for (int ni = 0; ni < 4; ni++) {
          int jl = wid * 4 + ni;
          const float* hp = &hb[pb * OSTR + jl * 4];
          f32x4 h0 = *(const f32x4*)hp;
          f32x4 h1 = *(const f32x4*)(hp + OSTR);
          f32x4 a = acc[mi][ni];
          oa[mi][0] += h0 * a[0];
          oa[mi][1] += h0 * a[1];
          oa[mi][2] += h1 * a[2];
          oa[mi][3] += h1 * a[3];
        }
      }
    }
  };

  // 17 j-blocks: 8 parity pairs + final even block (5 steps/jb flips parity)
#pragma unroll 1
  for (int jb2 = 0; jb2 < 8; jb2++) {
    jblock(2 * jb2,     br0, br1);
    jblock(2 * jb2 + 1, br1, br0);
  }
  jblock(16, br0, br1);

  // ---- cross-wave reduce of j-quarters (outr aliases A region) ----
  float* outr = (float*)sm.A;        // 64 x OSTR f32 = 17408 B <= 21504 B
  __syncthreads();                   // all compute done: A + hbuf dead
  if (wid == 0) {
#pragma unroll
    for (int mi = 0; mi < 4; mi++)
#pragma unroll
      for (int reg = 0; reg < 4; reg++) {
        int row = mi * 16 + (lane >> 4) * 4 + reg;
        *(f32x4*)&outr[row * OSTR + (lane & 15) * 4] = oa[mi][reg];
      }
  }
  __syncthreads();
#pragma unroll 1
  for (int r = 1; r < 4; r++) {
    if (wid == r) {
#pragma unroll
      for (int mi = 0; mi < 4; mi++)
#pragma unroll
        for (int reg = 0; reg < 4; reg++) {
          int row = mi * 16 + (lane >> 4) * 4 + reg;
          f32x4* dst = (f32x4*)&outr[row * OSTR + (lane & 15) * 4];
          *dst += oa[mi][reg];
        }
    }
    __syncthreads();
  }

  // ---- coalesced writeout: [n2][c][y][x], 64 contiguous floats per segment ----
  const int hh0 = bx / 3;            // p0/96
  const int ww0 = (bx - hh0 * 3) * 32;
#pragma unroll 1
  for (int i = 0; i < 16; i++) {
    int flat = i * 256 + tid;        // 0..4095
    int xl = flat & 63;
    int si = (flat >> 6) & 1;
    int c  = (flat >> 7) & 15;
    int n2 = flat >> 11;
    int pl = xl >> 1, sj = xl & 1;
    int q = si * 2 + sj;
    int row = pl * 2 + n2;
    float v = outr[row * OSTR + c * 4 + q];
    out[((n2 * 16 + c) * 192 + hh0 * 2 + si) * 192 + ww0 * 2 + xl] = v;
  }
}

// ---------------------------------------------------------------------------
extern "C" void kernel_launch(void* const* d_in, const int* in_sizes, int n_in,
                              void* d_out, int out_size, void* d_ws, size_t ws_size,
                              hipStream_t stream) {
  const float* x   = (const float*)d_in[0];
  const float* pos = (const float*)d_in[1];
  // d_in[2] = mask (all true) -- unused
  const float* w1  = (const float*)d_in[3];
  const float* b1  = (const float*)d_in[4];
  const float* w2  = (const float*)d_in[5];
  const float* b2  = (const float*)d_in[6];
  float* out = (float*)d_out;

  unsigned short* Aimg  = (unsigned short*)d_ws;   // 18432*160*2 = 5,898,240 B
  unsigned short* Btimg = Aimg + MROWS * KPAD;     // 4352*160*2  = 1,392,640 B

  // prep: 368640 + 87040 = 455680 = 1780 * 256
  ml_prep<<<1780, 256, 0, stream>>>(x, w2, b2, Aimg, Btimg);
  ml_main<<<288, 256, 0, stream>>>(Aimg, Btimg, pos, w1, b1, out);
}